// Round 12
// baseline (653.114 us; speedup 1.0000x reference)
//
#include <hip/hip_runtime.h>
#include <hip/hip_bf16.h>
#include <math.h>

#define NN 50000
#define EE 800000
#define HC 128
#define FF 32
#define NEG 0.2f
#define CAP 64
#define LOG2E 1.4426950408889634f
#define DUALB 784

__device__ __forceinline__ void fma4(float4& a, float s, const float4& w) {
    a.x = fmaf(s, w.x, a.x);
    a.y = fmaf(s, w.y, a.y);
    a.z = fmaf(s, w.z, a.z);
    a.w = fmaf(s, w.w, a.w);
}

// ---------------- dual linear work: xl = x@Wl+bl, xr = x@Wr+br ----------------
// One wave per 4 nodes per iteration. Lane l: half=l>>5 (xl/xr), cols
// 4*(l&31)..+3. Weight quads loaded from L1 once per 4 nodes (amortized);
// x rows (8 quads) replicated every 8 lanes, width-8 shfl broadcast.

__device__ __forceinline__ void dual_work(
        int bid, int nblocks, int t,
        const float* __restrict__ x,
        const float* __restrict__ Wl, const float* __restrict__ bl,
        const float* __restrict__ Wr, const float* __restrict__ br,
        float* __restrict__ xl, float* __restrict__ xr) {
    const int l = t & 63;
    const int half = l >> 5;
    const int lc = l & 31;
    const float* __restrict__ W  = half ? Wr : Wl;
    const float* __restrict__ bb = half ? br : bl;
    float* __restrict__ outp     = half ? xr : xl;
    const float4 bias = *(const float4*)(bb + 4 * lc);

    const int wv = bid * 4 + (t >> 6);
    const int nW = nblocks * 4;
    const int q8 = 4 * (l & 7);

    for (int n0 = wv * 4; n0 < NN; n0 += nW * 4) {
        float4 c0 = *(const float4*)(x + (size_t)n0 * 32 + q8);
        float4 c1 = *(const float4*)(x + (size_t)(n0 + 1) * 32 + q8);
        float4 c2 = *(const float4*)(x + (size_t)(n0 + 2) * 32 + q8);
        float4 c3 = *(const float4*)(x + (size_t)(n0 + 3) * 32 + q8);
        float4 a0 = bias, a1 = bias, a2 = bias, a3 = bias;
#pragma unroll
        for (int q = 0; q < 8; ++q) {
            float4 w0 = *(const float4*)(W + (4 * q + 0) * 128 + 4 * lc);
            float4 w1 = *(const float4*)(W + (4 * q + 1) * 128 + 4 * lc);
            float4 w2 = *(const float4*)(W + (4 * q + 2) * 128 + 4 * lc);
            float4 w3 = *(const float4*)(W + (4 * q + 3) * 128 + 4 * lc);
            float s;
            s = __shfl(c0.x, q, 8); fma4(a0, s, w0);
            s = __shfl(c0.y, q, 8); fma4(a0, s, w1);
            s = __shfl(c0.z, q, 8); fma4(a0, s, w2);
            s = __shfl(c0.w, q, 8); fma4(a0, s, w3);
            s = __shfl(c1.x, q, 8); fma4(a1, s, w0);
            s = __shfl(c1.y, q, 8); fma4(a1, s, w1);
            s = __shfl(c1.z, q, 8); fma4(a1, s, w2);
            s = __shfl(c1.w, q, 8); fma4(a1, s, w3);
            s = __shfl(c2.x, q, 8); fma4(a2, s, w0);
            s = __shfl(c2.y, q, 8); fma4(a2, s, w1);
            s = __shfl(c2.z, q, 8); fma4(a2, s, w2);
            s = __shfl(c2.w, q, 8); fma4(a2, s, w3);
            s = __shfl(c3.x, q, 8); fma4(a3, s, w0);
            s = __shfl(c3.y, q, 8); fma4(a3, s, w1);
            s = __shfl(c3.z, q, 8); fma4(a3, s, w2);
            s = __shfl(c3.w, q, 8); fma4(a3, s, w3);
        }
        *(float4*)(outp + (size_t)n0 * 128 + 4 * lc) = a0;
        *(float4*)(outp + (size_t)(n0 + 1) * 128 + 4 * lc) = a1;
        *(float4*)(outp + (size_t)(n0 + 2) * 128 + 4 * lc) = a2;
        *(float4*)(outp + (size_t)(n0 + 3) * 128 + 4 * lc) = a3;
    }
}

__global__ __launch_bounds__(256) void k_dual(
        const float* __restrict__ x,
        const float* __restrict__ Wl, const float* __restrict__ bl,
        const float* __restrict__ Wr, const float* __restrict__ br,
        float* __restrict__ xl, float* __restrict__ xr) {
    dual_work(blockIdx.x, gridDim.x, threadIdx.x, x, Wl, bl, Wr, br, xl, xr);
}

// layer-0 dual + bucket build fused (independent work, block-range split)
__global__ __launch_bounds__(256) void k_pre(
        const float* __restrict__ x,
        const float* __restrict__ Wl, const float* __restrict__ bl,
        const float* __restrict__ Wr, const float* __restrict__ br,
        float* __restrict__ xl, float* __restrict__ xr,
        const int* __restrict__ src, const int* __restrict__ dst,
        const float* __restrict__ ea, int* __restrict__ cnt,
        int2* __restrict__ pairs) {
    if (blockIdx.x < DUALB) {
        dual_work(blockIdx.x, DUALB, threadIdx.x, x, Wl, bl, Wr, br, xl, xr);
    } else {
        int e = (blockIdx.x - DUALB) * 256 + threadIdx.x;
        if (e < EE) {
            int d = dst[e];
            int pos = atomicAdd(&cnt[d], 1);
            pairs[d * CAP + pos] = make_int2(src[e], __float_as_int(fabsf(ea[e])));
        }
    }
}

// ---------------- CSR fallback path ----------------

__global__ void k_hist(const int* __restrict__ dst, int* __restrict__ deg) {
    int e = blockIdx.x * 256 + threadIdx.x;
    if (e < EE) atomicAdd(&deg[dst[e]], 1);
}

__global__ void k_scan1(const int* __restrict__ deg, int* __restrict__ part) {
    __shared__ int sd[256];
    int b = blockIdx.x, t = threadIdx.x;
    int base = b * 1024 + t * 4;
    int s = 0;
#pragma unroll
    for (int i = 0; i < 4; ++i) { int idx = base + i; if (idx < NN) s += deg[idx]; }
    sd[t] = s; __syncthreads();
    for (int off = 128; off; off >>= 1) { if (t < off) sd[t] += sd[t + off]; __syncthreads(); }
    if (t == 0) part[b] = sd[0];
}

__global__ void k_scan2(int* __restrict__ part, int nb) {
    if (threadIdx.x == 0) {
        int run = 0;
        for (int i = 0; i < nb; ++i) { int v = part[i]; part[i] = run; run += v; }
    }
}

__global__ void k_scan3(const int* __restrict__ deg, const int* __restrict__ part,
                        int* __restrict__ rowptr) {
    __shared__ int sd[256];
    int b = blockIdx.x, t = threadIdx.x;
    int base = b * 1024 + t * 4;
    int v[4]; int mine = 0;
#pragma unroll
    for (int i = 0; i < 4; ++i) { int idx = base + i; v[i] = (idx < NN) ? deg[idx] : 0; mine += v[i]; }
    sd[t] = mine; __syncthreads();
    for (int off = 1; off < 256; off <<= 1) {
        int tmp = (t >= off) ? sd[t - off] : 0;
        __syncthreads();
        sd[t] += tmp;
        __syncthreads();
    }
    int run = sd[t] - mine + part[b];
#pragma unroll
    for (int i = 0; i < 4; ++i) { int idx = base + i; if (idx < NN) rowptr[idx] = run; run += v[i]; }
    if (b == 0 && t == 0) rowptr[NN] = EE;
}

__global__ void k_scatter(const int* __restrict__ src, const int* __restrict__ dst,
                          const float* __restrict__ ea, const int* __restrict__ rowptr,
                          int* __restrict__ fill, int2* __restrict__ pairs) {
    int e = blockIdx.x * 256 + threadIdx.x;
    if (e >= EE) return;
    int d = dst[e];
    int pos = rowptr[d] + atomicAdd(&fill[d], 1);
    pairs[pos] = make_int2(src[e], __float_as_int(fabsf(ea[e])));
}

// ---------------- fused GATv2 edge-softmax + aggregate + MLP/BN (+pool) ----------------
// Epilogue weights read directly from global (L1-resident 16 KB); LDS staging
// removed — ds_read_b128 of a [128][32] fp32 tile is a provable 4-way bank
// conflict (bank depends on column only; 32 lanes / 8 column-quads).

template<bool BUCKET, bool LAST>
__global__ __launch_bounds__(256) void k_gat_mlp(
        const float* __restrict__ xl, const float* __restrict__ xr,
        const int* __restrict__ idx,     // BUCKET: cnt[N]; CSR: rowptr[N+1]
        const int2* __restrict__ pairs,
        const float* __restrict__ att,   // [128]
        const float* __restrict__ Wev,   // [128]
        const float* __restrict__ cb,    // [128]
        const float* __restrict__ lW,    // [128][32]
        const float* __restrict__ lb,    // [32]
        const float* __restrict__ bsc, const float* __restrict__ bsh,
        float* __restrict__ hout,        // [N][32] (unused if LAST)
        float* __restrict__ part_g) {    // [64][32] (used if LAST)
    __shared__ float gp[FF];
    if (LAST) {
        if (threadIdx.x < 32) gp[threadIdx.x] = 0.f;
        __syncthreads();
    }

    const int l = threadIdx.x & 31;
    const int n = blockIdx.x * 8 + (threadIdx.x >> 5);
    const char* __restrict__ xlp = (const char*)xl + (l << 4);  // per-lane base

    float4 att4 = ((const float4*)att)[l];
    att4.x *= LOG2E; att4.y *= LOG2E; att4.z *= LOG2E; att4.w *= LOG2E;
    float4 we4  = ((const float4*)Wev)[l];
    float4 xr4  = ((const float4*)xr)[n * 32 + l];
    int beg, end;
    if (BUCKET) { beg = n * CAP; end = beg + idx[n]; }
    else        { beg = idx[n];  end = idx[n + 1]; }
    const int last = end - 1;

    float m = -INFINITY, s = 0.f;
    float4 acc = make_float4(0.f, 0.f, 0.f, 0.f);

    if (beg < end) {
        int2 p0 = pairs[beg];
        int2 p1 = pairs[beg + 1 < last ? beg + 1 : last];
        int2 p2 = pairs[beg + 2 < last ? beg + 2 : last];
        float4 x0 = *(const float4*)(xlp + (p0.x << 9));
        float4 x1 = *(const float4*)(xlp + (p1.x << 9));

#pragma unroll 2
        for (int j = beg; j <= last; ++j) {
            int jn = j + 3 < last ? j + 3 : last;
            int2 pn = pairs[jn];
            float4 xn = *(const float4*)(xlp + (p2.x << 9));

            float sea = __int_as_float(p0.y);
            float4 v;
            v.x = fmaf(sea, we4.x, xr4.x + x0.x);
            v.y = fmaf(sea, we4.y, xr4.y + x0.y);
            v.z = fmaf(sea, we4.z, xr4.z + x0.z);
            v.w = fmaf(sea, we4.w, xr4.w + x0.w);
            v.x = fmaxf(v.x, NEG * v.x);
            v.y = fmaxf(v.y, NEG * v.y);
            v.z = fmaxf(v.z, NEG * v.z);
            v.w = fmaxf(v.w, NEG * v.w);
            float pl = v.x * att4.x;              // log2 units
            pl = fmaf(v.y, att4.y, pl);
            pl = fmaf(v.z, att4.z, pl);
            pl = fmaf(v.w, att4.w, pl);
            pl += __shfl_xor(pl, 4);
            pl += __shfl_xor(pl, 2);
            pl += __shfl_xor(pl, 1);

            float mn = fmaxf(m, pl);
            float d  = __builtin_amdgcn_exp2f(fminf(m, pl) - mn);
            bool up  = pl > m;                    // exactly one of c,e is 1
            float c  = up ? d : 1.0f;
            float e  = up ? 1.0f : d;
            s = fmaf(s, c, e);
            acc.x = fmaf(acc.x, c, e * x0.x);
            acc.y = fmaf(acc.y, c, e * x0.y);
            acc.z = fmaf(acc.z, c, e * x0.z);
            acc.w = fmaf(acc.w, c, e * x0.w);
            m = mn;

            p0 = p1; p1 = p2; p2 = pn;
            x0 = x1; x1 = xn;
        }
    }

    float inv = (s > 0.f) ? 1.f / s : 0.f;
    float4 cb4 = ((const float4*)cb)[l];
    float4 o;
    o.x = fmaf(acc.x, inv, cb4.x);
    o.y = fmaf(acc.y, inv, cb4.y);
    o.z = fmaf(acc.z, inv, cb4.z);
    o.w = fmaf(acc.w, inv, cb4.w);

    // ---- fused MLP+BN epilogue (weights from global/L1) ----
    const int cg = (l >> 2) & 7;
    const int kg = l & 3;
    const int kg8 = kg * 8;
    float4 a2 = (kg == 0) ? *(const float4*)(lb + 4 * cg)
                          : make_float4(0.f, 0.f, 0.f, 0.f);
#pragma unroll 2
    for (int j = 0; j < 8; ++j) {
        float vx = __shfl(o.x, kg8 + j, 32);
        float vy = __shfl(o.y, kg8 + j, 32);
        float vz = __shfl(o.z, kg8 + j, 32);
        float vw = __shfl(o.w, kg8 + j, 32);
        const float* wp = lW + (32 * kg + 4 * j) * 32 + 4 * cg;
        float4 w0 = *(const float4*)(wp);
        float4 w1 = *(const float4*)(wp + 32);
        float4 w2 = *(const float4*)(wp + 64);
        float4 w3 = *(const float4*)(wp + 96);
        fma4(a2, vx, w0);
        fma4(a2, vy, w1);
        fma4(a2, vz, w2);
        fma4(a2, vw, w3);
    }
    a2.x += __shfl_xor(a2.x, 1); a2.x += __shfl_xor(a2.x, 2);
    a2.y += __shfl_xor(a2.y, 1); a2.y += __shfl_xor(a2.y, 2);
    a2.z += __shfl_xor(a2.z, 1); a2.z += __shfl_xor(a2.z, 2);
    a2.w += __shfl_xor(a2.w, 1); a2.w += __shfl_xor(a2.w, 2);

    if (kg == 0) {
        const float4 sc4 = *(const float4*)(bsc + 4 * cg);
        const float4 sh4 = *(const float4*)(bsh + 4 * cg);
        float4 hq;
        hq.x = fmaxf(a2.x, NEG * a2.x);
        hq.y = fmaxf(a2.y, NEG * a2.y);
        hq.z = fmaxf(a2.z, NEG * a2.z);
        hq.w = fmaxf(a2.w, NEG * a2.w);
        hq.x = fmaf(hq.x, sc4.x, sh4.x);
        hq.y = fmaf(hq.y, sc4.y, sh4.y);
        hq.z = fmaf(hq.z, sc4.z, sh4.z);
        hq.w = fmaf(hq.w, sc4.w, sh4.w);
        if (LAST) {
            atomicAdd(&gp[4 * cg + 0], hq.x);
            atomicAdd(&gp[4 * cg + 1], hq.y);
            atomicAdd(&gp[4 * cg + 2], hq.z);
            atomicAdd(&gp[4 * cg + 3], hq.w);
        } else {
            *(float4*)(hout + (size_t)n * 32 + 4 * cg) = hq;
        }
    }
    if (LAST) {
        __syncthreads();
        if (threadIdx.x < 32)
            atomicAdd(&part_g[(blockIdx.x & 63) * 32 + threadIdx.x], gp[threadIdx.x]);
    }
}

// ---------------- head MLP: reduce part_g[64][32]; 32 -> 256 -> 32 -> 2 ----------------

__global__ void k_head(const float* __restrict__ part_g,
                       const float* __restrict__ W1, const float* __restrict__ b1,
                       const float* __restrict__ W2, const float* __restrict__ b2,
                       const float* __restrict__ W3, const float* __restrict__ b3,
                       float* __restrict__ out) {
    __shared__ float red[256];
    __shared__ float gv[32];
    __shared__ float h1[256];
    __shared__ float h2[32];
    int t = threadIdx.x;
    int col = t & 31, r = t >> 5;
    float lsum = 0.f;
#pragma unroll
    for (int k = 0; k < 8; ++k) lsum += part_g[(r + 8 * k) * 32 + col];
    red[t] = lsum; __syncthreads();
    if (r < 4) red[t] += red[t + 128];
    __syncthreads();
    if (r < 2) red[t] += red[t + 64];
    __syncthreads();
    if (r < 1) gv[col] = (red[t] + red[t + 32]) * (1.0f / NN);
    __syncthreads();
    float acc = b1[t];
#pragma unroll 8
    for (int k = 0; k < 32; ++k) acc += gv[k] * W1[k * 256 + t];
    h1[t] = acc > 0.f ? acc : NEG * acc;
    __syncthreads();
    if (t < 32) {
        float a = b2[t];
        for (int k = 0; k < 256; ++k) a += h1[k] * W2[k * 32 + t];
        h2[t] = a > 0.f ? a : NEG * a;
    }
    __syncthreads();
    if (t < 2) {
        float a = b3[t];
#pragma unroll
        for (int k = 0; k < 32; ++k) a += h2[k] * W3[k * 2 + t];
        out[t] = a;
    }
}

// ---------------- host ----------------

static inline size_t alignup(size_t x) { return (x + 255) & ~size_t(255); }

extern "C" void kernel_launch(void* const* d_in, const int* in_sizes, int n_in,
                              void* d_out, int out_size, void* d_ws, size_t ws_size,
                              hipStream_t stream) {
    const float* x     = (const float*)d_in[0];
    const int*   eidx  = (const int*)d_in[1];
    const float* eattr = (const float*)d_in[2];
    const float* Wl    = (const float*)d_in[4];
    const float* bl    = (const float*)d_in[5];
    const float* Wr    = (const float*)d_in[6];
    const float* br    = (const float*)d_in[7];
    const float* att   = (const float*)d_in[8];
    const float* We    = (const float*)d_in[9];
    const float* cb    = (const float*)d_in[10];
    const float* lW    = (const float*)d_in[11];
    const float* lb    = (const float*)d_in[12];
    const float* bsc   = (const float*)d_in[13];
    const float* bsh   = (const float*)d_in[14];
    const float* W1    = (const float*)d_in[15];
    const float* b1    = (const float*)d_in[16];
    const float* W2    = (const float*)d_in[17];
    const float* b2    = (const float*)d_in[18];
    const float* W3    = (const float*)d_in[19];
    const float* b3    = (const float*)d_in[20];

    const int* srcp = eidx;
    const int* dstp = eidx + EE;

    char* ws = (char*)d_ws;
    size_t off = 0;
    float* xl = (float*)(ws + off); off += alignup((size_t)NN * HC * 4);
    float* xr = (float*)(ws + off); off += alignup((size_t)NN * HC * 4);
    float* hA = (float*)(ws + off); off += alignup((size_t)NN * FF * 4);
    float* hB = (float*)(ws + off); off += alignup((size_t)NN * FF * 4);

    // bucket layout: pairsB, then contiguous zeroed region {cntB, part_g}
    size_t boff = off;
    int2*  pairsB = (int2*) (ws + boff); boff += alignup((size_t)NN * CAP * 8);
    int*   cntB   = (int*)  (ws + boff); size_t z0 = boff; boff += alignup((size_t)NN * 4);
    float* partGB = (float*)(ws + boff); boff += alignup(64 * 32 * 4);
    const size_t zlenB = boff - z0;
    const bool bucket = (ws_size >= boff);

    const float* cur = x;
    float* hbuf[2] = {hA, hB};

    if (bucket) {
        hipMemsetAsync(cntB, 0, zlenB, stream);
        const int bucketBlocks = (EE + 255) / 256;  // 3125
        k_pre<<<DUALB + bucketBlocks, 256, 0, stream>>>(
            x, Wl, bl, Wr, br, xl, xr, srcp, dstp, eattr, cntB, pairsB);
        for (int i = 0; i < 3; ++i) {
            if (i > 0)
                k_dual<<<DUALB, 256, 0, stream>>>(cur, Wl + i * FF * HC, bl + i * HC,
                                                  Wr + i * FF * HC, br + i * HC, xl, xr);
            if (i < 2)
                k_gat_mlp<true, false><<<NN / 8, 256, 0, stream>>>(
                    xl, xr, cntB, pairsB, att + i * HC, We + i * HC, cb + i * HC,
                    lW + i * HC * FF, lb + i * FF, bsc + i * FF, bsh + i * FF,
                    hbuf[i & 1], partGB);
            else
                k_gat_mlp<true, true><<<NN / 8, 256, 0, stream>>>(
                    xl, xr, cntB, pairsB, att + i * HC, We + i * HC, cb + i * HC,
                    lW + i * HC * FF, lb + i * FF, bsc + i * FF, bsh + i * FF,
                    hbuf[i & 1], partGB);
            cur = hbuf[i & 1];
        }
        k_head<<<1, 256, 0, stream>>>(partGB, W1, b1, W2, b2, W3, b3, (float*)d_out);
    } else {
        // CSR fallback
        size_t coff = off;
        int2*  pairsC = (int2*) (ws + coff); coff += alignup((size_t)EE * 8);
        int*   rowptr = (int*)  (ws + coff); coff += alignup((size_t)(NN + 1) * 4);
        int*   deg    = (int*)  (ws + coff); size_t z1 = coff; coff += alignup((size_t)NN * 4);
        int*   fill   = (int*)  (ws + coff); coff += alignup((size_t)NN * 4);
        int*   part   = (int*)  (ws + coff); coff += alignup(64 * 4);
        float* partGC = (float*)(ws + coff); coff += alignup(64 * 32 * 4);
        const size_t zlenC = coff - z1;

        hipMemsetAsync(deg, 0, zlenC, stream);
        const int nChunk = (NN + 1023) / 1024;  // 49
        k_hist<<<(EE + 255) / 256, 256, 0, stream>>>(dstp, deg);
        k_scan1<<<nChunk, 256, 0, stream>>>(deg, part);
        k_scan2<<<1, 64, 0, stream>>>(part, nChunk);
        k_scan3<<<nChunk, 256, 0, stream>>>(deg, part, rowptr);
        k_scatter<<<(EE + 255) / 256, 256, 0, stream>>>(srcp, dstp, eattr, rowptr, fill, pairsC);

        for (int i = 0; i < 3; ++i) {
            k_dual<<<DUALB, 256, 0, stream>>>(cur, Wl + i * FF * HC, bl + i * HC,
                                              Wr + i * FF * HC, br + i * HC, xl, xr);
            if (i < 2)
                k_gat_mlp<false, false><<<NN / 8, 256, 0, stream>>>(
                    xl, xr, rowptr, pairsC, att + i * HC, We + i * HC, cb + i * HC,
                    lW + i * HC * FF, lb + i * FF, bsc + i * FF, bsh + i * FF,
                    hbuf[i & 1], partGC);
            else
                k_gat_mlp<false, true><<<NN / 8, 256, 0, stream>>>(
                    xl, xr, rowptr, pairsC, att + i * HC, We + i * HC, cb + i * HC,
                    lW + i * HC * FF, lb + i * FF, bsc + i * FF, bsh + i * FF,
                    hbuf[i & 1], partGC);
            cur = hbuf[i & 1];
        }
        k_head<<<1, 256, 0, stream>>>(partGC, W1, b1, W2, b2, W3, b3, (float*)d_out);
    }
}